// Round 7
// baseline (114.994 us; speedup 1.0000x reference)
//
#include <hip/hip_runtime.h>

// Problem dims (fixed by reference)
#define BB 4
#define LL 1024
#define DD 64
#define UU 32
#define TI 8     // query rows per block
#define NT 512   // threads per block (8 waves)
#define JH 512   // j's per half (j-split: 2 halves)

// ---------------------------------------------------------------------------
// K1: Ekt[b,u4,j] = float4 of exp(2*(inp@Wx)) for u=4*u4..4*u4+3 (transposed:
// lane-consecutive j -> coalesced float4 loads in attn phase A).
// tanh(q+k+bh) = 1 - 2/(1 + Eq*Ek); Eq is computed per-block inside attn.
// ---------------------------------------------------------------------------
__global__ __launch_bounds__(256) void precompute_kernel(
    const float* __restrict__ inp, const float* __restrict__ Wx,
    float* __restrict__ Ekt)
{
    __shared__ float s_in[8][DD];       // 2 KB
    __shared__ float s_wx[DD][UU];      // 8 KB
    __shared__ float s_ek[8][36];       // padded: conflict-free b128 reads
    int t = threadIdx.x;
    int row0 = blockIdx.x * 8;
    if (t < 128)
        ((float4*)s_in)[t] = ((const float4*)(inp + (size_t)row0 * DD))[t];
#pragma unroll
    for (int p = 0; p < 2; ++p)
        ((float4*)s_wx)[p * 256 + t] = ((const float4*)Wx)[p * 256 + t];
    __syncthreads();
    int r = t >> 5;
    int u = t & 31;
    float k = 0.f;
#pragma unroll
    for (int d = 0; d < DD; ++d)
        k = fmaf(s_in[r][d], s_wx[d][u], k);
    s_ek[r][u] = __expf(2.f * k);
    __syncthreads();
    // transposed write: Ekt[(b*8 + u4)*LL + l] (float4 units)
    if (t < 64) {
        int u4 = t >> 3, r2 = t & 7;
        float4 v = *(const float4*)(&s_ek[r2][u4 * 4]);
        size_t gr = row0 + r2;
        size_t bb_ = gr >> 10, l = gr & 1023;
        ((float4*)Ekt)[(bb_ * 8 + u4) * LL + l] = v;
    }
}

// ---------------------------------------------------------------------------
// K2: j-split partial attention. Block = (rowblk, jh): TI=8 rows x 512 j's.
// grid = 2 * B*L/TI = 1024 blocks.
// KEY CHANGE vs R6: ALL 8 Ekt quads loaded up-front into registers before the
// u4 loop (one latency exposure instead of 8 barrier-synchronized convoy
// stalls). Phase A has zero global loads in the loop body.
// ---------------------------------------------------------------------------
union ShMem {
    struct { float wt[DD][UU]; float in[TI][DD]; } pre;   // 10 KB (staging)
    struct { float a[JH][TI]; } sm;                        // 16 KB (ex table)
    float4 v[8][TI][16];                                   // 16 KB (epilogue)
};

__global__ __launch_bounds__(NT) void attn_partial_kernel(
    const float* __restrict__ Ekt, const float* __restrict__ inp,
    const float* __restrict__ Wt, const float* __restrict__ Wa,
    const float* __restrict__ bh,
    float* __restrict__ po, float* __restrict__ pm, float* __restrict__ ps)
{
    __shared__ ShMem sh;
    __shared__ float s_eq[TI][UU];      // 1 KB, live through phase A
    __shared__ float s_red[2][8][TI];   // [stage][wave][row]

    int t      = threadIdx.x;
    int w      = t >> 6;                // wave 0..7
    int bid    = blockIdx.x;
    int rowblk = bid >> 1;              // 0..511
    int jh     = bid & 1;               // j-half
    int b      = rowblk >> 7;
    int i0     = (rowblk & 127) * TI;
    int j0     = jh * JH;

    // ---------------- Phase 0: stage inp rows + Wt, compute Eq tile ---------
    if (t < 128)
        ((float4*)sh.pre.in)[t] =
            ((const float4*)(inp + (size_t)(b * LL + i0) * DD))[t];
    ((float4*)sh.pre.wt)[t] = ((const float4*)Wt)[t];   // 512 float4 = all of Wt
    __syncthreads();                                             // B0
    if (t < TI * UU) {
        int i = t >> 5, u = t & 31;
        float q = 0.f;
#pragma unroll
        for (int d = 0; d < DD; ++d)
            q = fmaf(sh.pre.in[i][d], sh.pre.wt[d][u], q);
        s_eq[i][u] = __expf(2.f * (q + bh[u]));
    }
    __syncthreads();                                             // B0b

    // ---------------- Phase A: all Ekt quads up-front, then pure compute ----
    const float4* ektb = (const float4*)Ekt + (size_t)b * 8 * LL;
    float4 ek[8];
#pragma unroll
    for (int u4 = 0; u4 < 8; ++u4)
        ek[u4] = ektb[u4 * LL + j0 + t];       // 8 coalesced b128, one wait

    float acc[TI];
#pragma unroll
    for (int i = 0; i < TI; ++i) acc[i] = 0.f;

#pragma unroll
    for (int u4 = 0; u4 < 8; ++u4) {
        float4 wav = *(const float4*)(Wa + u4 * 4);  // uniform -> s_load
        float wa0 = wav.x, wa1 = wav.y, wa2 = wav.z, wa3 = wav.w;
        float4 cur = ek[u4];
#pragma unroll
        for (int i = 0; i < TI; ++i) {
            float4 eqv = *(const float4*)(&s_eq[i][u4 * 4]);   // b128 broadcast
            float p  = fmaf(eqv.x, cur.x, 1.f);
            float q  = fmaf(eqv.y, cur.y, 1.f);
            float r  = fmaf(eqv.z, cur.z, 1.f);
            float s  = fmaf(eqv.w, cur.w, 1.f);
            float n01 = fmaf(wa0, q, wa1 * p);
            float n23 = fmaf(wa2, s, wa3 * r);
            float pq = p * q, rs = r * s;
            float num = fmaf(n01, rs, n23 * pq);
            float den = pq * rs;                     // <= ~4e22, safe in fp32
            acc[i] = fmaf(num, __builtin_amdgcn_rcpf(den), acc[i]);
        }
    }

    float ev[TI];
#pragma unroll
    for (int i = 0; i < TI; ++i) ev[i] = -2.f * acc[i];

    // ---------------- Partial softmax: local max + local sum ----------------
    float wred[TI];
#pragma unroll
    for (int i = 0; i < TI; ++i) {
        float v = ev[i];
#pragma unroll
        for (int m = 32; m >= 1; m >>= 1) v = fmaxf(v, __shfl_xor(v, m, 64));
        wred[i] = v;
    }
    if ((t & 63) == 0) {
#pragma unroll
        for (int i = 0; i < TI; ++i) s_red[0][w][i] = wred[i];
    }
    __syncthreads();                                             // B1
    float m[TI];
#pragma unroll
    for (int i = 0; i < TI; ++i) {
        float v = s_red[0][0][i];
#pragma unroll
        for (int w2 = 1; w2 < 8; ++w2) v = fmaxf(v, s_red[0][w2][i]);
        m[i] = v;
    }

#pragma unroll
    for (int i = 0; i < TI; ++i) {
        ev[i] = __expf(ev[i] - m[i]);     // unnormalized ex
        float s = ev[i];
#pragma unroll
        for (int mm = 32; mm >= 1; mm >>= 1) s += __shfl_xor(s, mm, 64);
        wred[i] = s;
    }
    if ((t & 63) == 0) {
#pragma unroll
        for (int i = 0; i < TI; ++i) s_red[1][w][i] = wred[i];
    }
    __syncthreads();                                             // B2
    float sl[TI];
#pragma unroll
    for (int i = 0; i < TI; ++i) {
        float s = 0.f;
#pragma unroll
        for (int w2 = 0; w2 < 8; ++w2) s += s_red[1][w2][i];
        sl[i] = s;
    }
    if (t == 0) {
#pragma unroll
        for (int i = 0; i < TI; ++i) {
            pm[rowblk * 16 + jh * 8 + i] = m[i];
            ps[rowblk * 16 + jh * 8 + i] = sl[i];
        }
    }

    // ex table to LDS: s_a[jl][i]
    {
        float4 lo, hi;
        lo.x = ev[0]; lo.y = ev[1]; lo.z = ev[2]; lo.w = ev[3];
        hi.x = ev[4]; hi.y = ev[5]; hi.z = ev[6]; hi.w = ev[7];
        *(float4*)(&sh.sm.a[t][0]) = lo;
        *(float4*)(&sh.sm.a[t][4]) = hi;
    }
    __syncthreads();                                             // B3

    // ---------------- Phase B: po = ex @ x over this j-half -----------------
    int dq = t & 15;        // d-quad
    int g  = t >> 4;        // j-group 0..31
    const float4* inp4 = (const float4*)(inp + (size_t)b * LL * DD);
    float4 v[TI];
#pragma unroll
    for (int i = 0; i < TI; ++i) v[i] = (float4){0.f, 0.f, 0.f, 0.f};

    float4 xbuf[4];
#pragma unroll
    for (int p = 0; p < 4; ++p)
        xbuf[p] = inp4[(size_t)(j0 + p * 32 + g) * 16 + dq];

#pragma unroll 2
    for (int jo = 0; jo < 4; ++jo) {
#pragma unroll
        for (int p = 0; p < 4; ++p) {
            int jj = jo * 4 + p;
            int jl = jj * 32 + g;
            float4 x = xbuf[p];
            if (jo < 3) xbuf[p] = inp4[(size_t)(j0 + (jj + 4) * 32 + g) * 16 + dq];
            float4 a0 = *(const float4*)(&sh.sm.a[jl][0]);   // b128 broadcast
            float4 a1 = *(const float4*)(&sh.sm.a[jl][4]);
            v[0].x = fmaf(a0.x, x.x, v[0].x); v[0].y = fmaf(a0.x, x.y, v[0].y);
            v[0].z = fmaf(a0.x, x.z, v[0].z); v[0].w = fmaf(a0.x, x.w, v[0].w);
            v[1].x = fmaf(a0.y, x.x, v[1].x); v[1].y = fmaf(a0.y, x.y, v[1].y);
            v[1].z = fmaf(a0.y, x.z, v[1].z); v[1].w = fmaf(a0.y, x.w, v[1].w);
            v[2].x = fmaf(a0.z, x.x, v[2].x); v[2].y = fmaf(a0.z, x.y, v[2].y);
            v[2].z = fmaf(a0.z, x.z, v[2].z); v[2].w = fmaf(a0.z, x.w, v[2].w);
            v[3].x = fmaf(a0.w, x.x, v[3].x); v[3].y = fmaf(a0.w, x.y, v[3].y);
            v[3].z = fmaf(a0.w, x.z, v[3].z); v[3].w = fmaf(a0.w, x.w, v[3].w);
            v[4].x = fmaf(a1.x, x.x, v[4].x); v[4].y = fmaf(a1.x, x.y, v[4].y);
            v[4].z = fmaf(a1.x, x.z, v[4].z); v[4].w = fmaf(a1.x, x.w, v[4].w);
            v[5].x = fmaf(a1.y, x.x, v[5].x); v[5].y = fmaf(a1.y, x.y, v[5].y);
            v[5].z = fmaf(a1.y, x.z, v[5].z); v[5].w = fmaf(a1.y, x.w, v[5].w);
            v[6].x = fmaf(a1.z, x.x, v[6].x); v[6].y = fmaf(a1.z, x.y, v[6].y);
            v[6].z = fmaf(a1.z, x.z, v[6].z); v[6].w = fmaf(a1.z, x.w, v[6].w);
            v[7].x = fmaf(a1.w, x.x, v[7].x); v[7].y = fmaf(a1.w, x.y, v[7].y);
            v[7].z = fmaf(a1.w, x.z, v[7].z); v[7].w = fmaf(a1.w, x.w, v[7].w);
        }
    }

    // reduce 4 j-groups within each wave (lanes differ in bits 4,5 of t)
#pragma unroll
    for (int i = 0; i < TI; ++i) {
        v[i].x += __shfl_xor(v[i].x, 16, 64); v[i].y += __shfl_xor(v[i].y, 16, 64);
        v[i].z += __shfl_xor(v[i].z, 16, 64); v[i].w += __shfl_xor(v[i].w, 16, 64);
        v[i].x += __shfl_xor(v[i].x, 32, 64); v[i].y += __shfl_xor(v[i].y, 32, 64);
        v[i].z += __shfl_xor(v[i].z, 32, 64); v[i].w += __shfl_xor(v[i].w, 32, 64);
    }
    __syncthreads();                     // B4: a-reads done before union reuse
    if ((t & 63) < 16) {
#pragma unroll
        for (int i = 0; i < TI; ++i) sh.v[w][i][dq] = v[i];
    }
    __syncthreads();                                             // B5

    // final cross-wave reduce + coalesced store of partial o
    int i = t >> 6;       // 0..7
    int d = t & 63;       // 0..63
    const float* svf = (const float*)sh.v;
    float r = 0.f;
#pragma unroll
    for (int w2 = 0; w2 < 8; ++w2) r += svf[w2 * (TI * 64) + i * 64 + d];
    po[(size_t)bid * (TI * DD) + i * DD + d] = r;
}

// ---------------------------------------------------------------------------
// K3: merge the two j-halves: out = (o0*w0 + o1*w1) / (s0*w0 + s1*w1 + 1e-8)
// with w_h = exp(m_h - max(m0,m1)). Exactly the reference's ex/(sum+1e-8).
// ---------------------------------------------------------------------------
__global__ __launch_bounds__(256) void combine_kernel(
    const float* __restrict__ po, const float* __restrict__ pm,
    const float* __restrict__ ps, float* __restrict__ out)
{
    int gid    = blockIdx.x * 256 + threadIdx.x;   // 0 .. B*L*DD-1
    int d      = gid & 63;
    int row    = gid >> 6;          // 0..4095
    int rowblk = row >> 3;
    int i      = row & 7;
    float m0 = pm[rowblk * 16 + i],     m1 = pm[rowblk * 16 + 8 + i];
    float s0 = ps[rowblk * 16 + i],     s1 = ps[rowblk * 16 + 8 + i];
    float m  = fmaxf(m0, m1);
    float w0 = __expf(m0 - m), w1 = __expf(m1 - m);
    float s  = fmaf(s0, w0, s1 * w1) + 1e-8f;
    float o0 = po[(size_t)(rowblk * 2 + 0) * 512 + i * 64 + d];
    float o1 = po[(size_t)(rowblk * 2 + 1) * 512 + i * 64 + d];
    out[(size_t)row * DD + d] = fmaf(o0, w0, o1 * w1) * __builtin_amdgcn_rcpf(s);
}

// ---------------------------------------------------------------------------
extern "C" void kernel_launch(void* const* d_in, const int* in_sizes, int n_in,
                              void* d_out, int out_size, void* d_ws, size_t ws_size,
                              hipStream_t stream) {
    const float* inp = (const float*)d_in[0];
    const float* Wt  = (const float*)d_in[1];
    const float* Wx  = (const float*)d_in[2];
    const float* Wa  = (const float*)d_in[3];
    const float* bh  = (const float*)d_in[4];
    // d_in[5] = ba (cancels in softmax), d_in[6] = attention_width (dead code)
    float* out = (float*)d_out;

    float* Ekt = (float*)d_ws;                        // 512 KB
    float* po  = Ekt + (size_t)BB * LL * UU;          // 1024 * 512 floats = 2 MB
    float* pm  = po + (size_t)1024 * TI * DD;         // 16 KB
    float* ps  = pm + (size_t)512 * 16;               // 16 KB

    precompute_kernel<<<BB * LL / 8, 256, 0, stream>>>(inp, Wx, Ekt);
    attn_partial_kernel<<<2 * BB * LL / TI, NT, 0, stream>>>(
        Ekt, inp, Wt, Wa, bh, po, pm, ps);
    combine_kernel<<<BB * LL * DD / 256, 256, 0, stream>>>(po, pm, ps, out);
}

// Round 8
// 99.708 us; speedup vs baseline: 1.1533x; 1.1533x over previous
//
#include <hip/hip_runtime.h>

// Problem dims (fixed by reference)
#define BB 4
#define LL 1024
#define DD 64
#define UU 32
#define NW 4      // waves per block = query rows per block (1 row per wave)
#define NT 256    // threads per block
#define JH 512    // j's per half (j-split: 2 halves)
#define NTILE 8   // JH / 64

// ---------------------------------------------------------------------------
// K1: Ekt[b,u4,j] = float4 of exp(2*(inp@Wx)) for u=4*u4..4*u4+3 (transposed:
// lane-consecutive j -> coalesced float4 loads in attn phase A).
// tanh(q+k+bh) = 1 - 2/(1 + Eq*Ek); Eq computed per-block inside attn.
// ---------------------------------------------------------------------------
__global__ __launch_bounds__(256) void precompute_kernel(
    const float* __restrict__ inp, const float* __restrict__ Wx,
    float* __restrict__ Ekt)
{
    __shared__ float s_in[8][DD];       // 2 KB
    __shared__ float s_wx[DD][UU];      // 8 KB
    __shared__ float s_ek[8][36];       // padded: conflict-free b128 reads
    int t = threadIdx.x;
    int row0 = blockIdx.x * 8;
    if (t < 128)
        ((float4*)s_in)[t] = ((const float4*)(inp + (size_t)row0 * DD))[t];
#pragma unroll
    for (int p = 0; p < 2; ++p)
        ((float4*)s_wx)[p * 256 + t] = ((const float4*)Wx)[p * 256 + t];
    __syncthreads();
    int r = t >> 5;
    int u = t & 31;
    float k = 0.f;
#pragma unroll
    for (int d = 0; d < DD; ++d)
        k = fmaf(s_in[r][d], s_wx[d][u], k);
    s_ek[r][u] = __expf(2.f * k);
    __syncthreads();
    if (t < 64) {
        int u4 = t >> 3, r2 = t & 7;
        float4 v = *(const float4*)(&s_ek[r2][u4 * 4]);
        size_t gr = row0 + r2;
        size_t bb_ = gr >> 10, l = gr & 1023;
        ((float4*)Ekt)[(bb_ * 8 + u4) * LL + l] = v;
    }
}

// ---------------------------------------------------------------------------
// K2: wave-per-row j-split partial attention.
// block = 4 waves = 4 rows x 512 j's; grid = 2 * B*L/4 = 2048 blocks
// (= exactly 8 blocks/CU: whole grid co-resident, 32 waves/CU).
// Phase A: eq in SGPRs (v_readlane), ek from global (coalesced), e -> LDS.
// Softmax: pure in-wave shuffle reduce (no barriers, no cross-wave traffic).
// ---------------------------------------------------------------------------
__global__ __launch_bounds__(NT) void attn_partial_kernel(
    const float* __restrict__ Ekt, const float* __restrict__ inp,
    const float* __restrict__ Wt, const float* __restrict__ Wa,
    const float* __restrict__ bh,
    float* __restrict__ po, float* __restrict__ pm, float* __restrict__ ps)
{
    __shared__ union {
        struct { float wt[DD][UU]; float in[NW][DD]; } pre;  // 9.25 KB staging
        float a[NW][JH];                                      // 8 KB ex table
    } sh;
    __shared__ float  s_eq[NW][UU];     // 512 B
    __shared__ float4 s_v[NW][NW][16];  // 4 KB epilogue partials

    int t    = threadIdx.x;
    int w    = t >> 6;                  // wave 0..3 = local row
    int lane = t & 63;
    int bid  = blockIdx.x;
    int q    = bid >> 1;                // row-quad 0..1023
    int h    = bid & 1;                 // j-half
    int b    = q >> 8;
    int i0   = (q & 255) * NW;
    int j0   = h * JH;

    // ---------------- Phase 0: stage inp rows + Wt, compute Eq tile ---------
    if (t < 64)
        ((float4*)sh.pre.in)[t] =
            ((const float4*)(inp + (size_t)(b * LL + i0) * DD))[t];
    ((float4*)sh.pre.wt)[t]       = ((const float4*)Wt)[t];
    ((float4*)sh.pre.wt)[t + 256] = ((const float4*)Wt)[t + 256];
    __syncthreads();                                             // B0
    if (t < NW * UU) {
        int r = t >> 5, u = t & 31;
        float qq = 0.f;
#pragma unroll
        for (int d = 0; d < DD; ++d)
            qq = fmaf(sh.pre.in[r][d], sh.pre.wt[d][u], qq);
        s_eq[r][u] = __expf(2.f * (qq + bh[u]));
    }
    __syncthreads();    // B1: eq ready; pre-union dead -> sh.a writable

    // eq for THIS wave's row -> 32 SGPRs via readlane (lane u holds eq[u])
    float eqv = s_eq[w][lane & 31];
    float sq[UU];
#pragma unroll
    for (int u = 0; u < UU; ++u)
        sq[u] = __uint_as_float(
            __builtin_amdgcn_readlane(__float_as_uint(eqv), u));

    // ---------------- Phase A: scores, zero LDS reads, zero barriers --------
    const float4* ektb = (const float4*)Ekt + (size_t)b * 8 * LL;
    float rmax = -3.4e38f;
#pragma unroll 2
    for (int tile = 0; tile < NTILE; ++tile) {
        int jj = j0 + tile * 64 + lane;
        float4 ek[8];
#pragma unroll
        for (int u4 = 0; u4 < 8; ++u4) ek[u4] = ektb[u4 * LL + jj];
        float acc = 0.f;
#pragma unroll
        for (int u4 = 0; u4 < 8; ++u4) {
            float4 wav = *(const float4*)(Wa + u4 * 4);   // hoisted s_load
            float p  = fmaf(sq[u4 * 4 + 0], ek[u4].x, 1.f);
            float qq = fmaf(sq[u4 * 4 + 1], ek[u4].y, 1.f);
            float r  = fmaf(sq[u4 * 4 + 2], ek[u4].z, 1.f);
            float s  = fmaf(sq[u4 * 4 + 3], ek[u4].w, 1.f);
            float n01 = fmaf(wav.x, qq, wav.y * p);
            float n23 = fmaf(wav.z, s, wav.w * r);
            float pq = p * qq, rs = r * s;
            float num = fmaf(n01, rs, n23 * pq);
            acc = fmaf(num, __builtin_amdgcn_rcpf(pq * rs), acc);
        }
        float e = -2.f * acc;
        rmax = fmaxf(rmax, e);
        sh.a[w][tile * 64 + lane] = e;    // row-private: no barrier needed
    }

    // ---------------- In-wave partial softmax (this half) -------------------
#pragma unroll
    for (int m2 = 32; m2 >= 1; m2 >>= 1)
        rmax = fmaxf(rmax, __shfl_xor(rmax, m2, 64));
    float sum = 0.f;
#pragma unroll
    for (int tile = 0; tile < NTILE; ++tile) {
        float e  = sh.a[w][tile * 64 + lane];   // same-thread readback
        float ex = __expf(e - rmax);
        sum += ex;
        sh.a[w][tile * 64 + lane] = ex;         // unnormalized weights
    }
#pragma unroll
    for (int m2 = 32; m2 >= 1; m2 >>= 1)
        sum += __shfl_xor(sum, m2, 64);
    if (lane == 0) {
        pm[bid * NW + w] = rmax;
        ps[bid * NW + w] = sum;
    }
    __syncthreads();                    // B2: full a-table visible block-wide

    // ---------------- Phase B: po = ex @ x over this j-half -----------------
    int dq = t & 15;        // d-quad
    int g  = t >> 4;        // j-group 0..15
    const float4* inp4 = (const float4*)(inp + (size_t)b * LL * DD);
    float4 v[NW];
#pragma unroll
    for (int i = 0; i < NW; ++i) v[i] = (float4){0.f, 0.f, 0.f, 0.f};

#pragma unroll 4
    for (int jj = 0; jj < JH / 16; ++jj) {
        int jl = jj * 16 + g;
        float4 x  = inp4[(size_t)(j0 + jl) * 16 + dq];
        float a0 = sh.a[0][jl], a1 = sh.a[1][jl];
        float a2 = sh.a[2][jl], a3 = sh.a[3][jl];
        v[0].x = fmaf(a0, x.x, v[0].x); v[0].y = fmaf(a0, x.y, v[0].y);
        v[0].z = fmaf(a0, x.z, v[0].z); v[0].w = fmaf(a0, x.w, v[0].w);
        v[1].x = fmaf(a1, x.x, v[1].x); v[1].y = fmaf(a1, x.y, v[1].y);
        v[1].z = fmaf(a1, x.z, v[1].z); v[1].w = fmaf(a1, x.w, v[1].w);
        v[2].x = fmaf(a2, x.x, v[2].x); v[2].y = fmaf(a2, x.y, v[2].y);
        v[2].z = fmaf(a2, x.z, v[2].z); v[2].w = fmaf(a2, x.w, v[2].w);
        v[3].x = fmaf(a3, x.x, v[3].x); v[3].y = fmaf(a3, x.y, v[3].y);
        v[3].z = fmaf(a3, x.z, v[3].z); v[3].w = fmaf(a3, x.w, v[3].w);
    }

    // reduce the 4 j-groups within each wave (lane bits 4,5)
#pragma unroll
    for (int i = 0; i < NW; ++i) {
        v[i].x += __shfl_xor(v[i].x, 16, 64); v[i].y += __shfl_xor(v[i].y, 16, 64);
        v[i].z += __shfl_xor(v[i].z, 16, 64); v[i].w += __shfl_xor(v[i].w, 16, 64);
        v[i].x += __shfl_xor(v[i].x, 32, 64); v[i].y += __shfl_xor(v[i].y, 32, 64);
        v[i].z += __shfl_xor(v[i].z, 32, 64); v[i].w += __shfl_xor(v[i].w, 32, 64);
    }
    if (lane < 16) {
#pragma unroll
        for (int i = 0; i < NW; ++i) s_v[w][i][dq] = v[i];
    }
    __syncthreads();                                             // B3

    // final cross-wave reduce + coalesced store of partial o
    int i = t >> 6;       // 0..3
    int d = t & 63;       // 0..63
    const float* svf = (const float*)s_v;
    float r = 0.f;
#pragma unroll
    for (int w2 = 0; w2 < NW; ++w2) r += svf[w2 * (NW * 64) + i * 64 + d];
    po[(size_t)bid * (NW * DD) + i * DD + d] = r;
}

// ---------------------------------------------------------------------------
// K3: merge halves: out = (o0*w0 + o1*w1) / (s0*w0 + s1*w1 + 1e-8),
// w_h = exp(m_h - max(m0,m1)). Matches the reference's ex/(sum+1e-8).
// ---------------------------------------------------------------------------
__global__ __launch_bounds__(256) void combine_kernel(
    const float* __restrict__ po, const float* __restrict__ pm,
    const float* __restrict__ ps, float* __restrict__ out)
{
    int gid = blockIdx.x * 256 + threadIdx.x;   // 0 .. B*L*DD-1
    int d   = gid & 63;
    int row = gid >> 6;          // 0..4095
    int q   = row >> 2;          // row-quad
    int i   = row & 3;
    int b0  = q * 2, b1 = q * 2 + 1;
    float m0 = pm[b0 * NW + i], m1 = pm[b1 * NW + i];
    float s0 = ps[b0 * NW + i], s1 = ps[b1 * NW + i];
    float m  = fmaxf(m0, m1);
    float w0 = __expf(m0 - m), w1 = __expf(m1 - m);
    float s  = fmaf(s0, w0, s1 * w1) + 1e-8f;
    float o0 = po[(size_t)b0 * (NW * DD) + i * DD + d];
    float o1 = po[(size_t)b1 * (NW * DD) + i * DD + d];
    out[(size_t)row * DD + d] = fmaf(o0, w0, o1 * w1) * __builtin_amdgcn_rcpf(s);
}

// ---------------------------------------------------------------------------
extern "C" void kernel_launch(void* const* d_in, const int* in_sizes, int n_in,
                              void* d_out, int out_size, void* d_ws, size_t ws_size,
                              hipStream_t stream) {
    const float* inp = (const float*)d_in[0];
    const float* Wt  = (const float*)d_in[1];
    const float* Wx  = (const float*)d_in[2];
    const float* Wa  = (const float*)d_in[3];
    const float* bh  = (const float*)d_in[4];
    // d_in[5] = ba (cancels in softmax), d_in[6] = attention_width (dead code)
    float* out = (float*)d_out;

    float* Ekt = (float*)d_ws;                        // 512 KB
    float* po  = Ekt + (size_t)BB * LL * UU;          // 2048*256 floats = 2 MB
    float* pm  = po + (size_t)2048 * NW * DD;         // 32 KB
    float* ps  = pm + (size_t)2048 * NW;              // 32 KB

    precompute_kernel<<<BB * LL / 8, 256, 0, stream>>>(inp, Wx, Ekt);
    attn_partial_kernel<<<2 * BB * LL / NW, NT, 0, stream>>>(
        Ekt, inp, Wt, Wa, bh, po, pm, ps);
    combine_kernel<<<BB * LL * DD / 256, 256, 0, stream>>>(po, pm, ps, out);
}